// Round 13
// baseline (140.021 us; speedup 1.0000x reference)
//
#include <hip/hip_runtime.h>

#define T_TOKENS 8192
#define DMODEL   1024
#define NEXP     8

#define BM 256   // tokens per tile
#define BN 256   // features per tile
#define BK 64    // k per iteration (2 K-half phases of 32)
#define NITER (DMODEL / BK)

typedef float f32x4  __attribute__((ext_vector_type(4)));
typedef short short8 __attribute__((ext_vector_type(8)));

__device__ __forceinline__ unsigned short f32_to_bf16(float f) {
    unsigned int u = __builtin_bit_cast(unsigned int, f);
    unsigned int r = 0x7FFFu + ((u >> 16) & 1u);
    return (unsigned short)((u + r) >> 16);
}

// ---------------------------------------------------------------------------
// Kernel 1 (fused): blocks [0,2048) = gating; blocks [2048,4096) = We
// transpose to wt [E][f][d] bf16 (vectorized).
// ---------------------------------------------------------------------------
__global__ __launch_bounds__(256)
void prep(const float* __restrict__ x, const float* __restrict__ Wg,
          const float* __restrict__ We,
          unsigned short* __restrict__ xb, unsigned short* __restrict__ wt,
          int* __restrict__ top_e, float* __restrict__ top_w) {
    __shared__ unsigned short tile[64][72];
    const int bid = blockIdx.x;

    if (bid < 2048) {
        const int wave = threadIdx.x >> 6;
        const int lane = threadIdx.x & 63;
        const int t = bid * 4 + wave;

        float lg[8];
        #pragma unroll
        for (int e = 0; e < 8; ++e) lg[e] = 0.0f;

        const float* xr = x + (size_t)t * DMODEL;
        unsigned short* xo = xb + (size_t)t * DMODEL;

        #pragma unroll
        for (int j = 0; j < 4; ++j) {
            const int d = j * 256 + lane * 4;
            float4 xv = *reinterpret_cast<const float4*>(xr + d);
            ushort4 o;
            o.x = f32_to_bf16(xv.x);
            o.y = f32_to_bf16(xv.y);
            o.z = f32_to_bf16(xv.z);
            o.w = f32_to_bf16(xv.w);
            *reinterpret_cast<ushort4*>(xo + d) = o;
            const float xs[4] = {xv.x, xv.y, xv.z, xv.w};
            #pragma unroll
            for (int c = 0; c < 4; ++c) {
                const float4 wlo = *reinterpret_cast<const float4*>(Wg + (size_t)(d + c) * 8);
                const float4 whi = *reinterpret_cast<const float4*>(Wg + (size_t)(d + c) * 8 + 4);
                lg[0] += xs[c] * wlo.x;  lg[1] += xs[c] * wlo.y;
                lg[2] += xs[c] * wlo.z;  lg[3] += xs[c] * wlo.w;
                lg[4] += xs[c] * whi.x;  lg[5] += xs[c] * whi.y;
                lg[6] += xs[c] * whi.z;  lg[7] += xs[c] * whi.w;
            }
        }
        #pragma unroll
        for (int off = 1; off < 64; off <<= 1) {
            #pragma unroll
            for (int e = 0; e < 8; ++e) lg[e] += __shfl_xor(lg[e], off);
        }

        if (lane == 0) {
            int i1 = 0; float v1 = lg[0];
            #pragma unroll
            for (int e = 1; e < 8; ++e) if (lg[e] > v1) { v1 = lg[e]; i1 = e; }
            int i2 = -1; float v2 = -1e30f;
            #pragma unroll
            for (int e = 0; e < 8; ++e) if (e != i1 && lg[e] > v2) { v2 = lg[e]; i2 = e; }
            const float w1 = 1.0f / (1.0f + __expf(v2 - v1));
            top_e[t] = i1 | (i2 << 4);
            top_w[t] = w1;
        }
    } else {
        const int idx = bid - 2048;
        const int e   = idx >> 8;
        const int rem = idx & 255;
        const int d0  = (rem >> 4) * 64;
        const int f0  = (rem & 15) * 64;
        const float* src = We + ((size_t)e * DMODEL + d0) * DMODEL + f0;
        #pragma unroll
        for (int j = 0; j < 4; ++j) {
            const int ix = j * 256 + threadIdx.x;
            const int dl = ix >> 4;
            const int fq = ix & 15;
            float4 v = *reinterpret_cast<const float4*>(src + (size_t)dl * DMODEL + fq * 4);
            tile[fq * 4 + 0][dl] = f32_to_bf16(v.x);
            tile[fq * 4 + 1][dl] = f32_to_bf16(v.y);
            tile[fq * 4 + 2][dl] = f32_to_bf16(v.z);
            tile[fq * 4 + 3][dl] = f32_to_bf16(v.w);
        }
        __syncthreads();
        unsigned short* dst = wt + ((size_t)e * DMODEL + f0) * DMODEL + d0;
        #pragma unroll
        for (int j = 0; j < 4; ++j) {
            const int ix = j * 256 + threadIdx.x;
            const int fl = ix >> 4;
            const int dq = ix & 15;
            ushort4 v = *reinterpret_cast<const ushort4*>(&tile[fl][dq * 4]);
            *reinterpret_cast<ushort4*>(dst + (size_t)fl * DMODEL + dq * 4) = v;
        }
    }
}

// ---------------------------------------------------------------------------
// Kernel 2: compact — grid (E, 32), single pass, zero atomics.
// ---------------------------------------------------------------------------
__global__ __launch_bounds__(256)
void compact(const int* __restrict__ top_e, const float* __restrict__ top_w,
             int* __restrict__ counts, int* __restrict__ toks,
             float* __restrict__ wgts, int* __restrict__ rows) {
    const int e    = blockIdx.x;
    const int c    = blockIdx.y;
    const int tid  = threadIdx.x;
    const int wave = tid >> 6;
    const int lane = tid & 63;

    __shared__ int sm[256];
    __shared__ int red[4];
    __shared__ int ws[4];

    int mc = 0;
    const int4* tp = reinterpret_cast<const int4*>(top_e) + tid * 8;
    #pragma unroll
    for (int i = 0; i < 8; ++i) {
        int4 v = tp[i];
        mc += (((v.x & 15) == e) || (((v.x >> 4) & 15) == e)) ? 1 : 0;
        mc += (((v.y & 15) == e) || (((v.y >> 4) & 15) == e)) ? 1 : 0;
        mc += (((v.z & 15) == e) || (((v.z >> 4) & 15) == e)) ? 1 : 0;
        mc += (((v.w & 15) == e) || (((v.w >> 4) & 15) == e)) ? 1 : 0;
    }
    sm[tid] = mc;
    __syncthreads();

    int v = (tid < c * 8) ? sm[tid] : 0;
    #pragma unroll
    for (int off = 1; off < 64; off <<= 1) v += __shfl_xor(v, off);
    if (lane == 0) red[wave] = v;
    __syncthreads();
    const int base = red[0] + red[1] + red[2] + red[3];

    const int t  = c * 256 + tid;
    const int te = top_e[t];
    const int e1 = te & 15;
    const int e2 = (te >> 4) & 15;
    const bool m = (e1 == e) || (e2 == e);
    const unsigned long long b = __ballot(m);
    const int pos_in_wave = __popcll(b & ((1ull << lane) - 1ull));
    if (lane == 0) ws[wave] = __popcll(b);
    __syncthreads();

    int woff = base;
    #pragma unroll
    for (int i = 0; i < 4; ++i) if (i < wave) woff += ws[i];

    if (m) {
        const int pos = woff + pos_in_wave;
        const float w1 = top_w[t];
        toks[e * T_TOKENS + pos] = t;
        wgts[e * T_TOKENS + pos] = (e1 == e) ? w1 : 1.0f - w1;
        rows[t * 2 + ((e1 == e) ? 0 : 1)] = e * T_TOKENS + pos;
    }
    if (c == 31 && tid == 0)
        counts[e] = base + ws[0] + ws[1] + ws[2] + ws[3];
}

// ---------------------------------------------------------------------------
// Kernel 3: per-expert gather-GEMM — 256^2 tile, counted-vmcnt double-buffer
// pipeline (T3-lite + T4 + T5). r12 showed 256^2 with a full-drain 2-phase
// loop is stall-bound at 1 block/CU; this schedule replaces TLP with ILP:
// stage always lands 2 K-tiles ahead, entry wait is vmcnt(4) (never 0 except
// the last iter), 2 barriers/iter.
//
// LDS [2 buf][A,B][2 kh][256 rows x 64 B] = 128 KB (kh-major so each staged
// region is LINEAR -> global_load_lds-compatible). Swizzle ((row>>1)&3)<<4
// on the 64-B rows; bank-enumerated: 2-way only (free). Same involution on
// pre-swizzled global source and ds_read.
//
// Schedule per iter t (buf b = t&1, reads kt t; kt = BK=64 K-slab):
//   entry: vmcnt(4 | 8@t0 | 0@t15); s_barrier
//   [t in 1..14]  stage(buf b^1, kh1, kt t+1)   // 4 loads
//   phase kh0: 12 ds_read + 32 MFMA (setprio-wrapped)
//   s_barrier
//   [t <= 13]     stage(buf b,   kh0, kt t+2)   // 4 loads
//   phase kh1: 12 ds_read + 32 MFMA
// FIFO accounting/wave: prologue 16 outstanding; steady 12 after entry-issue;
// vmcnt(4) at entry == everything through kt t fully landed. WAR: every
// overwritten region's last reader is the phase immediately before a barrier
// (ds_reads lgkm-drained before that phase's MFMA).
//   D[f][p] = sum_k wt[e][f][k] * xb[tok[p]][k]
// ---------------------------------------------------------------------------
__global__ __launch_bounds__(512, 2)
void expert_gemm(const unsigned short* __restrict__ xb,
                 const unsigned short* __restrict__ wt,
                 const float* __restrict__ be,
                 const int* __restrict__ counts,
                 const int* __restrict__ toks,
                 const float* __restrict__ wgts,
                 unsigned short* __restrict__ hpart) {
    // Expert-major XCD remap (r11: FETCH 110->29 MB): e = flat%8.
    const int flat = blockIdx.x + 32 * (blockIdx.y + 4 * blockIdx.z);
    const int e    = flat & 7;
    const int rest = flat >> 3;
    const int fy   = rest & 3;
    const int tx   = rest >> 2;

    const int cnt = counts[e];
    const int p0  = tx * BM;
    if (p0 >= cnt) return;
    const int f0  = fy * BN;

    // [buf][mat 0=A(wt) 1=B(xb)][kh][row*32 ushorts] = 128 KB
    __shared__ unsigned short lds[2][2][2][256 * 32];
    __shared__ int   tok_s[BM];
    __shared__ float wgt_s[BM];

    const int tid  = threadIdx.x;
    const int wave = tid >> 6;          // 0..7
    const int lane = tid & 63;

    if (tid < BM) {
        int p = p0 + tid;
        if (p < cnt) {
            tok_s[tid] = toks[e * T_TOKENS + p];
            wgt_s[tid] = wgts[e * T_TOKENS + p];
        } else {
            tok_s[tid] = 0;
            wgt_s[tid] = 0.0f;
        }
    }
    __syncthreads();

    // Staging sources (pre-swizzled cols). Instr s covers rows
    // (wave*2+s)*16 .. +15 of the 256-row tile; 4 lanes x 16 B per row.
    const char* asrc[2];
    const char* bsrc[2];
    #pragma unroll
    for (int s = 0; s < 2; ++s) {
        const int r   = (wave * 2 + s) * 16 + (lane >> 2);
        const int col = ((lane & 3) << 4) ^ (((r >> 1) & 3) << 4);
        asrc[s] = (const char*)wt + ((size_t)(e * DMODEL + f0 + r)) * 2048 + col;
        bsrc[s] = (const char*)xb + ((size_t)tok_s[r]) * 2048 + col;
    }

    // stage one (matA+matB, one kh) group: 4 global_load_lds per wave.
    auto stage = [&](int buf, int kh, int kbyte) {
        #pragma unroll
        for (int s = 0; s < 2; ++s) {
            __builtin_amdgcn_global_load_lds(
                (const __attribute__((address_space(1))) void*)(asrc[s] + kbyte + kh * 64),
                (__attribute__((address_space(3))) void*)((char*)&lds[buf][0][kh][0] + (wave * 2 + s) * 1024),
                16, 0, 0);
            __builtin_amdgcn_global_load_lds(
                (const __attribute__((address_space(1))) void*)(bsrc[s] + kbyte + kh * 64),
                (__attribute__((address_space(3))) void*)((char*)&lds[buf][1][kh][0] + (wave * 2 + s) * 1024),
                16, 0, 0);
        }
    };

    f32x4 acc[8][4] = {};

    const int wm = wave >> 2;          // 0..1: f sub-block (128 rows)
    const int wn = wave & 3;           // 0..3: p sub-block (64 rows)
    const int wf = wm * 128;
    const int wp = wn * 64;

    auto phase = [&](int buf, int kh) {
        short8 afr[8], bfr[4];
        const char* Ab = (const char*)&lds[buf][0][kh][0];
        const char* Bb = (const char*)&lds[buf][1][kh][0];
        #pragma unroll
        for (int mi = 0; mi < 8; ++mi) {
            const int row = wf + mi * 16 + (lane & 15);
            afr[mi] = *(const short8*)(Ab + row * 64 +
                        ((((lane >> 4)) << 4) ^ (((row >> 1) & 3) << 4)));
        }
        #pragma unroll
        for (int ni = 0; ni < 4; ++ni) {
            const int row = wp + ni * 16 + (lane & 15);
            bfr[ni] = *(const short8*)(Bb + row * 64 +
                        ((((lane >> 4)) << 4) ^ (((row >> 1) & 3) << 4)));
        }
        __builtin_amdgcn_s_setprio(1);
        #pragma unroll
        for (int mi = 0; mi < 8; ++mi)
            #pragma unroll
            for (int ni = 0; ni < 4; ++ni)
                asm("v_mfma_f32_16x16x32_bf16 %0, %1, %2, %0"
                    : "+v"(acc[mi][ni])
                    : "v"(afr[mi]), "v"(bfr[ni]));
        __builtin_amdgcn_s_setprio(0);
    };

    // Prologue: kt0 -> buf0, kt1 -> buf1 (16 loads/wave outstanding).
    stage(0, 0, 0);
    stage(0, 1, 0);
    stage(1, 0, 128);
    stage(1, 1, 128);

    #pragma unroll 1
    for (int t = 0; t < NITER; ++t) {
        const int b = t & 1;
        if (t == 0) {
            asm volatile("s_waitcnt vmcnt(8)" ::: "memory");   // kt0 landed
        } else if (t == NITER - 1) {
            asm volatile("s_waitcnt vmcnt(0)" ::: "memory");   // kt15 landed
        } else {
            asm volatile("s_waitcnt vmcnt(4)" ::: "memory");   // kt t landed
        }
        asm volatile("s_barrier" ::: "memory");
        if (t >= 1 && t <= NITER - 2) stage(b ^ 1, 1, (t + 1) * 128);
        phase(b, 0);
        asm volatile("s_barrier" ::: "memory");
        if (t <= NITER - 3) stage(b, 0, (t + 2) * 128);
        phase(b, 1);
    }

    // Epilogue: lane holds D[f][p] frag: f = (lane>>4)*4 + r, p = lane&15.
    #pragma unroll
    for (int ni = 0; ni < 4; ++ni) {
        const int pl = wp + ni * 16 + (lane & 15);
        const int p  = p0 + pl;
        if (p >= cnt) continue;
        const float w = wgt_s[pl];
        unsigned short* hr = hpart + (size_t)(e * T_TOKENS + p) * DMODEL + f0 + wf;
        #pragma unroll
        for (int mi = 0; mi < 8; ++mi) {
            const int fb = mi * 16 + ((lane >> 4) << 2);
            const float* ber = be + (size_t)e * DMODEL + f0 + wf + fb;
            ushort4 o;
            float v0 = acc[mi][ni][0] + ber[0]; v0 = v0 > 0.f ? v0 : 0.f;
            float v1 = acc[mi][ni][1] + ber[1]; v1 = v1 > 0.f ? v1 : 0.f;
            float v2 = acc[mi][ni][2] + ber[2]; v2 = v2 > 0.f ? v2 : 0.f;
            float v3 = acc[mi][ni][3] + ber[3]; v3 = v3 > 0.f ? v3 : 0.f;
            o.x = f32_to_bf16(v0 * w);
            o.y = f32_to_bf16(v1 * w);
            o.z = f32_to_bf16(v2 * w);
            o.w = f32_to_bf16(v3 * w);
            *reinterpret_cast<ushort4*>(hr + fb) = o;
        }
    }
}

// ---------------------------------------------------------------------------
// Kernel 4: combine — y[t] = hpart[rows[t][0]] + hpart[rows[t][1]]
// ---------------------------------------------------------------------------
__global__ __launch_bounds__(256)
void combine(const unsigned short* __restrict__ hpart,
             const int* __restrict__ rows,
             float* __restrict__ y) {
    const int t = blockIdx.x;
    const int r0 = rows[t * 2 + 0];
    const int r1 = rows[t * 2 + 1];
    const int f = threadIdx.x * 4;
    ushort4 a = *reinterpret_cast<const ushort4*>(hpart + (size_t)r0 * DMODEL + f);
    ushort4 b = *reinterpret_cast<const ushort4*>(hpart + (size_t)r1 * DMODEL + f);
    float4 o;
    o.x = __builtin_bit_cast(float, (unsigned)a.x << 16) + __builtin_bit_cast(float, (unsigned)b.x << 16);
    o.y = __builtin_bit_cast(float, (unsigned)a.y << 16) + __builtin_bit_cast(float, (unsigned)b.y << 16);
    o.z = __builtin_bit_cast(float, (unsigned)a.z << 16) + __builtin_bit_cast(float, (unsigned)b.z << 16);
    o.w = __builtin_bit_cast(float, (unsigned)a.w << 16) + __builtin_bit_cast(float, (unsigned)b.w << 16);
    *reinterpret_cast<float4*>(y + (size_t)t * DMODEL + f) = o;
}

// ---------------------------------------------------------------------------
extern "C" void kernel_launch(void* const* d_in, const int* in_sizes, int n_in,
                              void* d_out, int out_size, void* d_ws, size_t ws_size,
                              hipStream_t stream) {
    (void)in_sizes; (void)n_in; (void)out_size; (void)ws_size;
    const float* x  = (const float*)d_in[0];
    const float* Wg = (const float*)d_in[1];
    const float* We = (const float*)d_in[2];
    const float* be = (const float*)d_in[3];
    float* y = (float*)d_out;

    char* ws = (char*)d_ws;
    unsigned short* xb     = (unsigned short*)(ws);                       // 16 MB
    unsigned short* wt     = (unsigned short*)(ws + (16u << 20));         // 16 MB
    size_t off = (32u << 20);
    int*   counts = (int*)(ws + off);    off += 1024;
    int*   toks   = (int*)(ws + off);    off += (size_t)NEXP * T_TOKENS * 4;
    float* wgts   = (float*)(ws + off);  off += (size_t)NEXP * T_TOKENS * 4;
    int*   rows   = (int*)(ws + off);    off += (size_t)T_TOKENS * 2 * 4;
    int*   top_e  = (int*)(ws + off);    off += (size_t)T_TOKENS * 4;
    float* top_w  = (float*)(ws + off);
    unsigned short* hpart = (unsigned short*)(ws + (34u << 20));          // 32 MB

    prep<<<dim3(4096), 256, 0, stream>>>(x, Wg, We, xb, wt, top_e, top_w);
    compact<<<dim3(NEXP, 32), 256, 0, stream>>>(top_e, top_w, counts, toks, wgts, rows);
    expert_gemm<<<dim3(T_TOKENS / BM, DMODEL / BN, NEXP), 512, 0, stream>>>(
        xb, wt, be, counts, toks, wgts, hpart);
    combine<<<dim3(T_TOKENS), 256, 0, stream>>>(hpart, rows, y);
}

// Round 14
// 107.500 us; speedup vs baseline: 1.3025x; 1.3025x over previous
//
#include <hip/hip_runtime.h>

#define T_TOKENS 8192
#define DMODEL   1024
#define NEXP     8

#define BM 128   // tokens per tile
#define BN 128   // features per tile
#define BK 64    // k per step (proven r11 config: single 32 KB buffer)
#define NSTEP (DMODEL / BK)

typedef float f32x4  __attribute__((ext_vector_type(4)));
typedef short short8 __attribute__((ext_vector_type(8)));

__device__ __forceinline__ unsigned short f32_to_bf16(float f) {
    unsigned int u = __builtin_bit_cast(unsigned int, f);
    unsigned int r = 0x7FFFu + ((u >> 16) & 1u);
    return (unsigned short)((u + r) >> 16);
}

// ---------------------------------------------------------------------------
// Kernel 1 (fused): blocks [0,2048) = gating (fp32 logits, top-2, x->bf16);
// blocks [2048,4096) = We [E][d][f] fp32 -> wt [E][f][d] bf16 transpose
// (vectorized: float4 reads, ushort4 tile reads, ushort4 global writes).
// ---------------------------------------------------------------------------
__global__ __launch_bounds__(256)
void prep(const float* __restrict__ x, const float* __restrict__ Wg,
          const float* __restrict__ We,
          unsigned short* __restrict__ xb, unsigned short* __restrict__ wt,
          int* __restrict__ top_e, float* __restrict__ top_w) {
    __shared__ unsigned short tile[64][72];
    const int bid = blockIdx.x;

    if (bid < 2048) {
        const int wave = threadIdx.x >> 6;
        const int lane = threadIdx.x & 63;
        const int t = bid * 4 + wave;

        float lg[8];
        #pragma unroll
        for (int e = 0; e < 8; ++e) lg[e] = 0.0f;

        const float* xr = x + (size_t)t * DMODEL;
        unsigned short* xo = xb + (size_t)t * DMODEL;

        #pragma unroll
        for (int j = 0; j < 4; ++j) {
            const int d = j * 256 + lane * 4;
            float4 xv = *reinterpret_cast<const float4*>(xr + d);
            ushort4 o;
            o.x = f32_to_bf16(xv.x);
            o.y = f32_to_bf16(xv.y);
            o.z = f32_to_bf16(xv.z);
            o.w = f32_to_bf16(xv.w);
            *reinterpret_cast<ushort4*>(xo + d) = o;
            const float xs[4] = {xv.x, xv.y, xv.z, xv.w};
            #pragma unroll
            for (int c = 0; c < 4; ++c) {
                const float4 wlo = *reinterpret_cast<const float4*>(Wg + (size_t)(d + c) * 8);
                const float4 whi = *reinterpret_cast<const float4*>(Wg + (size_t)(d + c) * 8 + 4);
                lg[0] += xs[c] * wlo.x;  lg[1] += xs[c] * wlo.y;
                lg[2] += xs[c] * wlo.z;  lg[3] += xs[c] * wlo.w;
                lg[4] += xs[c] * whi.x;  lg[5] += xs[c] * whi.y;
                lg[6] += xs[c] * whi.z;  lg[7] += xs[c] * whi.w;
            }
        }
        #pragma unroll
        for (int off = 1; off < 64; off <<= 1) {
            #pragma unroll
            for (int e = 0; e < 8; ++e) lg[e] += __shfl_xor(lg[e], off);
        }

        if (lane == 0) {
            int i1 = 0; float v1 = lg[0];
            #pragma unroll
            for (int e = 1; e < 8; ++e) if (lg[e] > v1) { v1 = lg[e]; i1 = e; }
            int i2 = -1; float v2 = -1e30f;
            #pragma unroll
            for (int e = 0; e < 8; ++e) if (e != i1 && lg[e] > v2) { v2 = lg[e]; i2 = e; }
            const float w1 = 1.0f / (1.0f + __expf(v2 - v1));
            top_e[t] = i1 | (i2 << 4);
            top_w[t] = w1;
        }
    } else {
        const int idx = bid - 2048;
        const int e   = idx >> 8;
        const int rem = idx & 255;
        const int d0  = (rem >> 4) * 64;
        const int f0  = (rem & 15) * 64;
        const float* src = We + ((size_t)e * DMODEL + d0) * DMODEL + f0;
        #pragma unroll
        for (int j = 0; j < 4; ++j) {
            const int ix = j * 256 + threadIdx.x;
            const int dl = ix >> 4;
            const int fq = ix & 15;
            float4 v = *reinterpret_cast<const float4*>(src + (size_t)dl * DMODEL + fq * 4);
            tile[fq * 4 + 0][dl] = f32_to_bf16(v.x);
            tile[fq * 4 + 1][dl] = f32_to_bf16(v.y);
            tile[fq * 4 + 2][dl] = f32_to_bf16(v.z);
            tile[fq * 4 + 3][dl] = f32_to_bf16(v.w);
        }
        __syncthreads();
        unsigned short* dst = wt + ((size_t)e * DMODEL + f0) * DMODEL + d0;
        #pragma unroll
        for (int j = 0; j < 4; ++j) {
            const int ix = j * 256 + threadIdx.x;
            const int fl = ix >> 4;
            const int dq = ix & 15;
            ushort4 v = *reinterpret_cast<const ushort4*>(&tile[fl][dq * 4]);
            *reinterpret_cast<ushort4*>(dst + (size_t)fl * DMODEL + dq * 4) = v;
        }
    }
}

// ---------------------------------------------------------------------------
// Kernel 2: compact — grid (E, 32), single pass, zero atomics.
// ---------------------------------------------------------------------------
__global__ __launch_bounds__(256)
void compact(const int* __restrict__ top_e, const float* __restrict__ top_w,
             int* __restrict__ counts, int* __restrict__ toks,
             float* __restrict__ wgts, int* __restrict__ rows) {
    const int e    = blockIdx.x;
    const int c    = blockIdx.y;
    const int tid  = threadIdx.x;
    const int wave = tid >> 6;
    const int lane = tid & 63;

    __shared__ int sm[256];
    __shared__ int red[4];
    __shared__ int ws[4];

    int mc = 0;
    const int4* tp = reinterpret_cast<const int4*>(top_e) + tid * 8;
    #pragma unroll
    for (int i = 0; i < 8; ++i) {
        int4 v = tp[i];
        mc += (((v.x & 15) == e) || (((v.x >> 4) & 15) == e)) ? 1 : 0;
        mc += (((v.y & 15) == e) || (((v.y >> 4) & 15) == e)) ? 1 : 0;
        mc += (((v.z & 15) == e) || (((v.z >> 4) & 15) == e)) ? 1 : 0;
        mc += (((v.w & 15) == e) || (((v.w >> 4) & 15) == e)) ? 1 : 0;
    }
    sm[tid] = mc;
    __syncthreads();

    int v = (tid < c * 8) ? sm[tid] : 0;
    #pragma unroll
    for (int off = 1; off < 64; off <<= 1) v += __shfl_xor(v, off);
    if (lane == 0) red[wave] = v;
    __syncthreads();
    const int base = red[0] + red[1] + red[2] + red[3];

    const int t  = c * 256 + tid;
    const int te = top_e[t];
    const int e1 = te & 15;
    const int e2 = (te >> 4) & 15;
    const bool m = (e1 == e) || (e2 == e);
    const unsigned long long b = __ballot(m);
    const int pos_in_wave = __popcll(b & ((1ull << lane) - 1ull));
    if (lane == 0) ws[wave] = __popcll(b);
    __syncthreads();

    int woff = base;
    #pragma unroll
    for (int i = 0; i < 4; ++i) if (i < wave) woff += ws[i];

    if (m) {
        const int pos = woff + pos_in_wave;
        const float w1 = top_w[t];
        toks[e * T_TOKENS + pos] = t;
        wgts[e * T_TOKENS + pos] = (e1 == e) ? w1 : 1.0f - w1;
        rows[t * 2 + ((e1 == e) ? 0 : 1)] = e * T_TOKENS + pos;
    }
    if (c == 31 && tid == 0)
        counts[e] = base + ws[0] + ws[1] + ws[2] + ws[3];
}

// ---------------------------------------------------------------------------
// Kernel 3: per-expert gather-GEMM — r11 proven structure, restored verbatim:
// BM=BN=128, BK=64, SINGLE 32 KB LDS buffer (33.8 KB -> 4 blocks/CU, 16
// waves/CU), 2x __syncthreads per K-step, (row&7)<<4 swizzle (0 conflicts),
// expert-major XCD remap (e=flat%8: wt 2 MB L2-resident; fy-fast: xb tile
// reused 8x from L2 -> FETCH 29 MB). Benched 54.3 us / 633 TF = the 2-phase
// structure ceiling.
// r12/r13 lesson: 256^2 tiles regress here — at 1 block/CU the 2-phase loop
// has no TLP (82 us), and the counted-vmcnt port hit a register-class
// pathology (VGPR_Count 104 < 128 live acc -> compiler shuffled accumulators
// around the asm blocks; MfmaUtil 15%). 4-block TLP at 128^2 is what works.
//   D[f][p] = sum_k wt[e][f][k] * xb[tok[p]][k]
// ---------------------------------------------------------------------------
__global__ __launch_bounds__(256)
void expert_gemm(const unsigned short* __restrict__ xb,
                 const unsigned short* __restrict__ wt,
                 const float* __restrict__ be,
                 const int* __restrict__ counts,
                 const int* __restrict__ toks,
                 const float* __restrict__ wgts,
                 unsigned short* __restrict__ hpart) {
    const int flat = blockIdx.x + 64 * (blockIdx.y + 8 * blockIdx.z);
    const int e    = flat & 7;          // expert: constant per XCD
    const int rest = flat >> 3;
    const int fy   = rest & 7;          // feature tile: cycles fast
    const int tx   = rest >> 3;         // token tile: slow

    const int cnt = counts[e];
    const int p0  = tx * BM;
    if (p0 >= cnt) return;
    const int f0  = fy * BN;

    __shared__ unsigned short lds_w[BN * BK];  // [f][k], swizzled, 16 KB
    __shared__ unsigned short lds_x[BM * BK];  // [p][k], swizzled, 16 KB
    __shared__ int   tok_s[BM];
    __shared__ float wgt_s[BM];

    const int tid  = threadIdx.x;
    const int wave = tid >> 6;
    const int lane = tid & 63;

    if (tid < BM) {
        int p = p0 + tid;
        if (p < cnt) {
            tok_s[tid] = toks[e * T_TOKENS + p];
            wgt_s[tid] = wgts[e * T_TOKENS + p];
        } else {
            tok_s[tid] = 0;
            wgt_s[tid] = 0.0f;
        }
    }
    __syncthreads();

    // Per-lane staging sources, pre-swizzled so the linear global_load_lds
    // write produces the XOR-swizzled LDS layout.
    const char* wsrc[4];
    const char* xsrc[4];
    #pragma unroll
    for (int s = 0; s < 4; ++s) {
        const int q    = wave * 4 + s;
        const int row  = q * 8 + (lane >> 3);
        const int scol = ((lane & 7) << 4) ^ ((row & 7) << 4);
        wsrc[s] = (const char*)wt + ((size_t)(e * DMODEL + f0 + row) * DMODEL) * 2 + scol;
        xsrc[s] = (const char*)xb + ((size_t)tok_s[row] * DMODEL) * 2 + scol;
    }

    f32x4 acc[4][4] = {};

    const int wf = (wave & 1) * 64;   // feature sub-block of this wave
    const int wp = (wave >> 1) * 64;  // token sub-block of this wave

    #pragma unroll 1
    for (int t = 0; t < NSTEP; ++t) {
        const size_t ko = (size_t)t * BK * 2;
        #pragma unroll
        for (int s = 0; s < 4; ++s) {
            __builtin_amdgcn_global_load_lds(
                (const __attribute__((address_space(1))) void*)(wsrc[s] + ko),
                (__attribute__((address_space(3))) void*)((char*)lds_w + (wave * 4 + s) * 1024),
                16, 0, 0);
            __builtin_amdgcn_global_load_lds(
                (const __attribute__((address_space(1))) void*)(xsrc[s] + ko),
                (__attribute__((address_space(3))) void*)((char*)lds_x + (wave * 4 + s) * 1024),
                16, 0, 0);
        }
        __syncthreads();   // drains vmcnt -> tile visible to all waves

        #pragma unroll
        for (int kk = 0; kk < 2; ++kk) {
            short8 afr[4], bfr[4];
            #pragma unroll
            for (int mi = 0; mi < 4; ++mi) {
                const int row = wf + mi * 16 + (lane & 15);
                const int kb  = (kk * 64 + ((lane >> 4) << 4)) ^ ((row & 7) << 4);
                afr[mi] = *(const short8*)((const char*)lds_w + row * 128 + kb);
            }
            #pragma unroll
            for (int ni = 0; ni < 4; ++ni) {
                const int row = wp + ni * 16 + (lane & 15);
                const int kb  = (kk * 64 + ((lane >> 4) << 4)) ^ ((row & 7) << 4);
                bfr[ni] = *(const short8*)((const char*)lds_x + row * 128 + kb);
            }
            #pragma unroll
            for (int mi = 0; mi < 4; ++mi)
                #pragma unroll
                for (int ni = 0; ni < 4; ++ni)
                    asm("v_mfma_f32_16x16x32_bf16 %0, %1, %2, %0"
                        : "+v"(acc[mi][ni])
                        : "v"(afr[mi]), "v"(bfr[ni]));
        }
        __syncthreads();   // all waves done reading before next overwrite
    }

    // Epilogue: lane holds D[f][p] frag: f = (lane>>4)*4 + r, p = lane&15.
    #pragma unroll
    for (int ni = 0; ni < 4; ++ni) {
        const int pl = wp + ni * 16 + (lane & 15);
        const int p  = p0 + pl;
        if (p >= cnt) continue;
        const float w = wgt_s[pl];
        unsigned short* hr = hpart + (size_t)(e * T_TOKENS + p) * DMODEL + f0 + wf;
        #pragma unroll
        for (int mi = 0; mi < 4; ++mi) {
            const int fb = mi * 16 + ((lane >> 4) << 2);
            const float* ber = be + (size_t)e * DMODEL + f0 + wf + fb;
            ushort4 o;
            float v0 = acc[mi][ni][0] + ber[0]; v0 = v0 > 0.f ? v0 : 0.f;
            float v1 = acc[mi][ni][1] + ber[1]; v1 = v1 > 0.f ? v1 : 0.f;
            float v2 = acc[mi][ni][2] + ber[2]; v2 = v2 > 0.f ? v2 : 0.f;
            float v3 = acc[mi][ni][3] + ber[3]; v3 = v3 > 0.f ? v3 : 0.f;
            o.x = f32_to_bf16(v0 * w);
            o.y = f32_to_bf16(v1 * w);
            o.z = f32_to_bf16(v2 * w);
            o.w = f32_to_bf16(v3 * w);
            *reinterpret_cast<ushort4*>(hr + fb) = o;
        }
    }
}

// ---------------------------------------------------------------------------
// Kernel 4: combine — y[t] = hpart[rows[t][0]] + hpart[rows[t][1]]
// ---------------------------------------------------------------------------
__global__ __launch_bounds__(256)
void combine(const unsigned short* __restrict__ hpart,
             const int* __restrict__ rows,
             float* __restrict__ y) {
    const int t = blockIdx.x;
    const int r0 = rows[t * 2 + 0];
    const int r1 = rows[t * 2 + 1];
    const int f = threadIdx.x * 4;
    ushort4 a = *reinterpret_cast<const ushort4*>(hpart + (size_t)r0 * DMODEL + f);
    ushort4 b = *reinterpret_cast<const ushort4*>(hpart + (size_t)r1 * DMODEL + f);
    float4 o;
    o.x = __builtin_bit_cast(float, (unsigned)a.x << 16) + __builtin_bit_cast(float, (unsigned)b.x << 16);
    o.y = __builtin_bit_cast(float, (unsigned)a.y << 16) + __builtin_bit_cast(float, (unsigned)b.y << 16);
    o.z = __builtin_bit_cast(float, (unsigned)a.z << 16) + __builtin_bit_cast(float, (unsigned)b.z << 16);
    o.w = __builtin_bit_cast(float, (unsigned)a.w << 16) + __builtin_bit_cast(float, (unsigned)b.w << 16);
    *reinterpret_cast<float4*>(y + (size_t)t * DMODEL + f) = o;
}

// ---------------------------------------------------------------------------
extern "C" void kernel_launch(void* const* d_in, const int* in_sizes, int n_in,
                              void* d_out, int out_size, void* d_ws, size_t ws_size,
                              hipStream_t stream) {
    (void)in_sizes; (void)n_in; (void)out_size; (void)ws_size;
    const float* x  = (const float*)d_in[0];
    const float* Wg = (const float*)d_in[1];
    const float* We = (const float*)d_in[2];
    const float* be = (const float*)d_in[3];
    float* y = (float*)d_out;

    char* ws = (char*)d_ws;
    unsigned short* xb     = (unsigned short*)(ws);                       // 16 MB
    unsigned short* wt     = (unsigned short*)(ws + (16u << 20));         // 16 MB
    size_t off = (32u << 20);
    int*   counts = (int*)(ws + off);    off += 1024;
    int*   toks   = (int*)(ws + off);    off += (size_t)NEXP * T_TOKENS * 4;
    float* wgts   = (float*)(ws + off);  off += (size_t)NEXP * T_TOKENS * 4;
    int*   rows   = (int*)(ws + off);    off += (size_t)T_TOKENS * 2 * 4;
    int*   top_e  = (int*)(ws + off);    off += (size_t)T_TOKENS * 4;
    float* top_w  = (float*)(ws + off);
    unsigned short* hpart = (unsigned short*)(ws + (34u << 20));          // 32 MB

    prep<<<dim3(4096), 256, 0, stream>>>(x, Wg, We, xb, wt, top_e, top_w);
    compact<<<dim3(NEXP, 32), 256, 0, stream>>>(top_e, top_w, counts, toks, wgts, rows);
    expert_gemm<<<dim3(T_TOKENS / BM, DMODEL / BN, NEXP), 256, 0, stream>>>(
        xb, wt, be, counts, toks, wgts, hpart);
    combine<<<dim3(T_TOKENS), 256, 0, stream>>>(hpart, rows, y);
}

// Round 15
// 106.167 us; speedup vs baseline: 1.3189x; 1.0126x over previous
//
#include <hip/hip_runtime.h>

#define T_TOKENS 8192
#define DMODEL   1024
#define NEXP     8

#define BM 128   // tokens per tile
#define BN 128   // features per tile
#define BK 64    // k per step (proven r11 config: single 32 KB buffer)
#define NSTEP (DMODEL / BK)

typedef float f32x4  __attribute__((ext_vector_type(4)));
typedef short short8 __attribute__((ext_vector_type(8)));

__device__ __forceinline__ unsigned short f32_to_bf16(float f) {
    unsigned int u = __builtin_bit_cast(unsigned int, f);
    unsigned int r = 0x7FFFu + ((u >> 16) & 1u);
    return (unsigned short)((u + r) >> 16);
}

// ---------------------------------------------------------------------------
// Kernel 1 (fused): blocks [0,2048) = gating (fp32 logits, top-2, x->bf16);
// blocks [2048,4096) = We [E][d][f] fp32 -> wt [E][f][d] bf16 transpose
// (vectorized: float4 reads, ushort4 tile reads, ushort4 global writes).
// ---------------------------------------------------------------------------
__global__ __launch_bounds__(256)
void prep(const float* __restrict__ x, const float* __restrict__ Wg,
          const float* __restrict__ We,
          unsigned short* __restrict__ xb, unsigned short* __restrict__ wt,
          int* __restrict__ top_e, float* __restrict__ top_w) {
    __shared__ unsigned short tile[64][72];
    const int bid = blockIdx.x;

    if (bid < 2048) {
        const int wave = threadIdx.x >> 6;
        const int lane = threadIdx.x & 63;
        const int t = bid * 4 + wave;

        float lg[8];
        #pragma unroll
        for (int e = 0; e < 8; ++e) lg[e] = 0.0f;

        const float* xr = x + (size_t)t * DMODEL;
        unsigned short* xo = xb + (size_t)t * DMODEL;

        #pragma unroll
        for (int j = 0; j < 4; ++j) {
            const int d = j * 256 + lane * 4;
            float4 xv = *reinterpret_cast<const float4*>(xr + d);
            ushort4 o;
            o.x = f32_to_bf16(xv.x);
            o.y = f32_to_bf16(xv.y);
            o.z = f32_to_bf16(xv.z);
            o.w = f32_to_bf16(xv.w);
            *reinterpret_cast<ushort4*>(xo + d) = o;
            const float xs[4] = {xv.x, xv.y, xv.z, xv.w};
            #pragma unroll
            for (int c = 0; c < 4; ++c) {
                const float4 wlo = *reinterpret_cast<const float4*>(Wg + (size_t)(d + c) * 8);
                const float4 whi = *reinterpret_cast<const float4*>(Wg + (size_t)(d + c) * 8 + 4);
                lg[0] += xs[c] * wlo.x;  lg[1] += xs[c] * wlo.y;
                lg[2] += xs[c] * wlo.z;  lg[3] += xs[c] * wlo.w;
                lg[4] += xs[c] * whi.x;  lg[5] += xs[c] * whi.y;
                lg[6] += xs[c] * whi.z;  lg[7] += xs[c] * whi.w;
            }
        }
        #pragma unroll
        for (int off = 1; off < 64; off <<= 1) {
            #pragma unroll
            for (int e = 0; e < 8; ++e) lg[e] += __shfl_xor(lg[e], off);
        }

        if (lane == 0) {
            int i1 = 0; float v1 = lg[0];
            #pragma unroll
            for (int e = 1; e < 8; ++e) if (lg[e] > v1) { v1 = lg[e]; i1 = e; }
            int i2 = -1; float v2 = -1e30f;
            #pragma unroll
            for (int e = 0; e < 8; ++e) if (e != i1 && lg[e] > v2) { v2 = lg[e]; i2 = e; }
            const float w1 = 1.0f / (1.0f + __expf(v2 - v1));
            top_e[t] = i1 | (i2 << 4);
            top_w[t] = w1;
        }
    } else {
        const int idx = bid - 2048;
        const int e   = idx >> 8;
        const int rem = idx & 255;
        const int d0  = (rem >> 4) * 64;
        const int f0  = (rem & 15) * 64;
        const float* src = We + ((size_t)e * DMODEL + d0) * DMODEL + f0;
        #pragma unroll
        for (int j = 0; j < 4; ++j) {
            const int ix = j * 256 + threadIdx.x;
            const int dl = ix >> 4;
            const int fq = ix & 15;
            float4 v = *reinterpret_cast<const float4*>(src + (size_t)dl * DMODEL + fq * 4);
            tile[fq * 4 + 0][dl] = f32_to_bf16(v.x);
            tile[fq * 4 + 1][dl] = f32_to_bf16(v.y);
            tile[fq * 4 + 2][dl] = f32_to_bf16(v.z);
            tile[fq * 4 + 3][dl] = f32_to_bf16(v.w);
        }
        __syncthreads();
        unsigned short* dst = wt + ((size_t)e * DMODEL + f0) * DMODEL + d0;
        #pragma unroll
        for (int j = 0; j < 4; ++j) {
            const int ix = j * 256 + threadIdx.x;
            const int fl = ix >> 4;
            const int dq = ix & 15;
            ushort4 v = *reinterpret_cast<const ushort4*>(&tile[fl][dq * 4]);
            *reinterpret_cast<ushort4*>(dst + (size_t)fl * DMODEL + dq * 4) = v;
        }
    }
}

// ---------------------------------------------------------------------------
// Kernel 2: compact — grid (E, 32), single pass, zero atomics.
// ---------------------------------------------------------------------------
__global__ __launch_bounds__(256)
void compact(const int* __restrict__ top_e, const float* __restrict__ top_w,
             int* __restrict__ counts, int* __restrict__ toks,
             float* __restrict__ wgts, int* __restrict__ rows) {
    const int e    = blockIdx.x;
    const int c    = blockIdx.y;
    const int tid  = threadIdx.x;
    const int wave = tid >> 6;
    const int lane = tid & 63;

    __shared__ int sm[256];
    __shared__ int red[4];
    __shared__ int ws[4];

    int mc = 0;
    const int4* tp = reinterpret_cast<const int4*>(top_e) + tid * 8;
    #pragma unroll
    for (int i = 0; i < 8; ++i) {
        int4 v = tp[i];
        mc += (((v.x & 15) == e) || (((v.x >> 4) & 15) == e)) ? 1 : 0;
        mc += (((v.y & 15) == e) || (((v.y >> 4) & 15) == e)) ? 1 : 0;
        mc += (((v.z & 15) == e) || (((v.z >> 4) & 15) == e)) ? 1 : 0;
        mc += (((v.w & 15) == e) || (((v.w >> 4) & 15) == e)) ? 1 : 0;
    }
    sm[tid] = mc;
    __syncthreads();

    int v = (tid < c * 8) ? sm[tid] : 0;
    #pragma unroll
    for (int off = 1; off < 64; off <<= 1) v += __shfl_xor(v, off);
    if (lane == 0) red[wave] = v;
    __syncthreads();
    const int base = red[0] + red[1] + red[2] + red[3];

    const int t  = c * 256 + tid;
    const int te = top_e[t];
    const int e1 = te & 15;
    const int e2 = (te >> 4) & 15;
    const bool m = (e1 == e) || (e2 == e);
    const unsigned long long b = __ballot(m);
    const int pos_in_wave = __popcll(b & ((1ull << lane) - 1ull));
    if (lane == 0) ws[wave] = __popcll(b);
    __syncthreads();

    int woff = base;
    #pragma unroll
    for (int i = 0; i < 4; ++i) if (i < wave) woff += ws[i];

    if (m) {
        const int pos = woff + pos_in_wave;
        const float w1 = top_w[t];
        toks[e * T_TOKENS + pos] = t;
        wgts[e * T_TOKENS + pos] = (e1 == e) ? w1 : 1.0f - w1;
        rows[t * 2 + ((e1 == e) ? 0 : 1)] = e * T_TOKENS + pos;
    }
    if (c == 31 && tid == 0)
        counts[e] = base + ws[0] + ws[1] + ws[2] + ws[3];
}

// ---------------------------------------------------------------------------
// Kernel 3: per-expert gather-GEMM — r11 structure with ONE change: MFMA
// inline-asm accumulator constraint "+v" -> "+a".
// Evidence: VGPR_Count=64 < live acc(64)+frags(16)+addr(~20) -> with "+v"
// the compiler kept acc in AGPRs between asm sites and shuttled it through
// VGPRs around EVERY MFMA (v_accvgpr_read/write pairs, ~256 VALU cyc/step vs
// 160 cyc of MFMA) — matching MfmaUtil 25 / VALUBusy 15. "+a" lets the MFMA
// read/write C/D in AGPRs natively (ISA §10), killing the shuttle. Also
// explains r13's collapse (128 accs -> 2x shuttle).
//   D[f][p] = sum_k wt[e][f][k] * xb[tok[p]][k]
// ---------------------------------------------------------------------------
__global__ __launch_bounds__(256)
void expert_gemm(const unsigned short* __restrict__ xb,
                 const unsigned short* __restrict__ wt,
                 const float* __restrict__ be,
                 const int* __restrict__ counts,
                 const int* __restrict__ toks,
                 const float* __restrict__ wgts,
                 unsigned short* __restrict__ hpart) {
    const int flat = blockIdx.x + 64 * (blockIdx.y + 8 * blockIdx.z);
    const int e    = flat & 7;          // expert: constant per XCD
    const int rest = flat >> 3;
    const int fy   = rest & 7;          // feature tile: cycles fast
    const int tx   = rest >> 3;         // token tile: slow

    const int cnt = counts[e];
    const int p0  = tx * BM;
    if (p0 >= cnt) return;
    const int f0  = fy * BN;

    __shared__ unsigned short lds_w[BN * BK];  // [f][k], swizzled, 16 KB
    __shared__ unsigned short lds_x[BM * BK];  // [p][k], swizzled, 16 KB
    __shared__ int   tok_s[BM];
    __shared__ float wgt_s[BM];

    const int tid  = threadIdx.x;
    const int wave = tid >> 6;
    const int lane = tid & 63;

    if (tid < BM) {
        int p = p0 + tid;
        if (p < cnt) {
            tok_s[tid] = toks[e * T_TOKENS + p];
            wgt_s[tid] = wgts[e * T_TOKENS + p];
        } else {
            tok_s[tid] = 0;
            wgt_s[tid] = 0.0f;
        }
    }
    __syncthreads();

    // Per-lane staging sources, pre-swizzled so the linear global_load_lds
    // write produces the XOR-swizzled LDS layout.
    const char* wsrc[4];
    const char* xsrc[4];
    #pragma unroll
    for (int s = 0; s < 4; ++s) {
        const int q    = wave * 4 + s;
        const int row  = q * 8 + (lane >> 3);
        const int scol = ((lane & 7) << 4) ^ ((row & 7) << 4);
        wsrc[s] = (const char*)wt + ((size_t)(e * DMODEL + f0 + row) * DMODEL) * 2 + scol;
        xsrc[s] = (const char*)xb + ((size_t)tok_s[row] * DMODEL) * 2 + scol;
    }

    f32x4 acc[4][4] = {};

    const int wf = (wave & 1) * 64;   // feature sub-block of this wave
    const int wp = (wave >> 1) * 64;  // token sub-block of this wave

    #pragma unroll 1
    for (int t = 0; t < NSTEP; ++t) {
        const size_t ko = (size_t)t * BK * 2;
        #pragma unroll
        for (int s = 0; s < 4; ++s) {
            __builtin_amdgcn_global_load_lds(
                (const __attribute__((address_space(1))) void*)(wsrc[s] + ko),
                (__attribute__((address_space(3))) void*)((char*)lds_w + (wave * 4 + s) * 1024),
                16, 0, 0);
            __builtin_amdgcn_global_load_lds(
                (const __attribute__((address_space(1))) void*)(xsrc[s] + ko),
                (__attribute__((address_space(3))) void*)((char*)lds_x + (wave * 4 + s) * 1024),
                16, 0, 0);
        }
        __syncthreads();   // drains vmcnt -> tile visible to all waves

        #pragma unroll
        for (int kk = 0; kk < 2; ++kk) {
            short8 afr[4], bfr[4];
            #pragma unroll
            for (int mi = 0; mi < 4; ++mi) {
                const int row = wf + mi * 16 + (lane & 15);
                const int kb  = (kk * 64 + ((lane >> 4) << 4)) ^ ((row & 7) << 4);
                afr[mi] = *(const short8*)((const char*)lds_w + row * 128 + kb);
            }
            #pragma unroll
            for (int ni = 0; ni < 4; ++ni) {
                const int row = wp + ni * 16 + (lane & 15);
                const int kb  = (kk * 64 + ((lane >> 4) << 4)) ^ ((row & 7) << 4);
                bfr[ni] = *(const short8*)((const char*)lds_x + row * 128 + kb);
            }
            #pragma unroll
            for (int mi = 0; mi < 4; ++mi)
                #pragma unroll
                for (int ni = 0; ni < 4; ++ni)
                    asm("v_mfma_f32_16x16x32_bf16 %0, %1, %2, %0"
                        : "+a"(acc[mi][ni])
                        : "v"(afr[mi]), "v"(bfr[ni]));
        }
        __syncthreads();   // all waves done reading before next overwrite
    }

    // Epilogue: lane holds D[f][p] frag: f = (lane>>4)*4 + r, p = lane&15.
    #pragma unroll
    for (int ni = 0; ni < 4; ++ni) {
        const int pl = wp + ni * 16 + (lane & 15);
        const int p  = p0 + pl;
        if (p >= cnt) continue;
        const float w = wgt_s[pl];
        unsigned short* hr = hpart + (size_t)(e * T_TOKENS + p) * DMODEL + f0 + wf;
        #pragma unroll
        for (int mi = 0; mi < 4; ++mi) {
            const int fb = mi * 16 + ((lane >> 4) << 2);
            const float* ber = be + (size_t)e * DMODEL + f0 + wf + fb;
            ushort4 o;
            float v0 = acc[mi][ni][0] + ber[0]; v0 = v0 > 0.f ? v0 : 0.f;
            float v1 = acc[mi][ni][1] + ber[1]; v1 = v1 > 0.f ? v1 : 0.f;
            float v2 = acc[mi][ni][2] + ber[2]; v2 = v2 > 0.f ? v2 : 0.f;
            float v3 = acc[mi][ni][3] + ber[3]; v3 = v3 > 0.f ? v3 : 0.f;
            o.x = f32_to_bf16(v0 * w);
            o.y = f32_to_bf16(v1 * w);
            o.z = f32_to_bf16(v2 * w);
            o.w = f32_to_bf16(v3 * w);
            *reinterpret_cast<ushort4*>(hr + fb) = o;
        }
    }
}

// ---------------------------------------------------------------------------
// Kernel 4: combine — y[t] = hpart[rows[t][0]] + hpart[rows[t][1]]
// ---------------------------------------------------------------------------
__global__ __launch_bounds__(256)
void combine(const unsigned short* __restrict__ hpart,
             const int* __restrict__ rows,
             float* __restrict__ y) {
    const int t = blockIdx.x;
    const int r0 = rows[t * 2 + 0];
    const int r1 = rows[t * 2 + 1];
    const int f = threadIdx.x * 4;
    ushort4 a = *reinterpret_cast<const ushort4*>(hpart + (size_t)r0 * DMODEL + f);
    ushort4 b = *reinterpret_cast<const ushort4*>(hpart + (size_t)r1 * DMODEL + f);
    float4 o;
    o.x = __builtin_bit_cast(float, (unsigned)a.x << 16) + __builtin_bit_cast(float, (unsigned)b.x << 16);
    o.y = __builtin_bit_cast(float, (unsigned)a.y << 16) + __builtin_bit_cast(float, (unsigned)b.y << 16);
    o.z = __builtin_bit_cast(float, (unsigned)a.z << 16) + __builtin_bit_cast(float, (unsigned)b.z << 16);
    o.w = __builtin_bit_cast(float, (unsigned)a.w << 16) + __builtin_bit_cast(float, (unsigned)b.w << 16);
    *reinterpret_cast<float4*>(y + (size_t)t * DMODEL + f) = o;
}

// ---------------------------------------------------------------------------
extern "C" void kernel_launch(void* const* d_in, const int* in_sizes, int n_in,
                              void* d_out, int out_size, void* d_ws, size_t ws_size,
                              hipStream_t stream) {
    (void)in_sizes; (void)n_in; (void)out_size; (void)ws_size;
    const float* x  = (const float*)d_in[0];
    const float* Wg = (const float*)d_in[1];
    const float* We = (const float*)d_in[2];
    const float* be = (const float*)d_in[3];
    float* y = (float*)d_out;

    char* ws = (char*)d_ws;
    unsigned short* xb     = (unsigned short*)(ws);                       // 16 MB
    unsigned short* wt     = (unsigned short*)(ws + (16u << 20));         // 16 MB
    size_t off = (32u << 20);
    int*   counts = (int*)(ws + off);    off += 1024;
    int*   toks   = (int*)(ws + off);    off += (size_t)NEXP * T_TOKENS * 4;
    float* wgts   = (float*)(ws + off);  off += (size_t)NEXP * T_TOKENS * 4;
    int*   rows   = (int*)(ws + off);    off += (size_t)T_TOKENS * 2 * 4;
    int*   top_e  = (int*)(ws + off);    off += (size_t)T_TOKENS * 4;
    float* top_w  = (float*)(ws + off);
    unsigned short* hpart = (unsigned short*)(ws + (34u << 20));          // 32 MB

    prep<<<dim3(4096), 256, 0, stream>>>(x, Wg, We, xb, wt, top_e, top_w);
    compact<<<dim3(NEXP, 32), 256, 0, stream>>>(top_e, top_w, counts, toks, wgts, rows);
    expert_gemm<<<dim3(T_TOKENS / BM, DMODEL / BN, NEXP), 256, 0, stream>>>(
        xb, wt, be, counts, toks, wgts, hpart);
    combine<<<dim3(T_TOKENS), 256, 0, stream>>>(hpart, rows, y);
}